// Round 1
// baseline (696.512 us; speedup 1.0000x reference)
//
#include <hip/hip_runtime.h>

#define B_SZ 64
#define TAPE_N 262144
#define OUT_N 65536
#define FANIN 16

// ---------------------------------------------------------------------------
// Kernel A: copy the full tape into the output buffer (float4 vectorized).
// Scattered columns get overwritten by the compute kernel afterwards.
// ---------------------------------------------------------------------------
__global__ __launch_bounds__(256) void copy_tape_kernel(
    const float4* __restrict__ src, float4* __restrict__ dst, int n4)
{
    int i = blockIdx.x * blockDim.x + threadIdx.x;
    const int stride = gridDim.x * blockDim.x;
    for (; i < n4; i += stride) dst[i] = src[i];
}

// ---------------------------------------------------------------------------
// Kernel B: per-output-neuron gather + dot + activation + scatter.
// Thread layout: o = blockIdx.x*64 + (tid & 63)  (64 outputs per block)
//                bq = tid >> 6  (4 batch-quarters of 16 rows each)
// Each thread loads its 16 indices/weights once, then loops 16 batch rows
// with 16 independent gathers in flight per row.
// ---------------------------------------------------------------------------
__global__ __launch_bounds__(256) void neuron_kernel(
    const float* __restrict__ tape,
    const float* __restrict__ weights,
    const float* __restrict__ bias,
    const int*   __restrict__ input_indices,
    const int*   __restrict__ output_indices,
    const int*   __restrict__ act_ids,
    float* __restrict__ out)
{
    const int tid = threadIdx.x;
    const int o   = blockIdx.x * 64 + (tid & 63);
    const int bq  = tid >> 6;                      // 0..3

    // 16 indices + 16 weights for this output neuron (64B each, contiguous
    // across the 64 lanes of a wave -> coalesced line fetches)
    const int4*   ip = (const int4*)(input_indices + (size_t)o * FANIN);
    const float4* wp = (const float4*)(weights      + (size_t)o * FANIN);
    const int4   i0 = ip[0], i1 = ip[1], i2 = ip[2], i3 = ip[3];
    const float4 w0 = wp[0], w1 = wp[1], w2 = wp[2], w3 = wp[3];
    const float bs  = bias[o];
    const int   act = act_ids[o];
    const int   od  = output_indices[o];

    const int b0 = bq * 16;
    #pragma unroll 1
    for (int b = b0; b < b0 + 16; ++b) {
        const float* __restrict__ t = tape + (size_t)b * TAPE_N;
        // 16 independent gathers -> deep MLP, compiler can issue all before
        // the first s_waitcnt.
        float g0  = t[i0.x], g1  = t[i0.y], g2  = t[i0.z], g3  = t[i0.w];
        float g4  = t[i1.x], g5  = t[i1.y], g6  = t[i1.z], g7  = t[i1.w];
        float g8  = t[i2.x], g9  = t[i2.y], g10 = t[i2.z], g11 = t[i2.w];
        float g12 = t[i3.x], g13 = t[i3.y], g14 = t[i3.z], g15 = t[i3.w];

        float acc = bs;
        acc += g0*w0.x;  acc += g1*w0.y;  acc += g2*w0.z;  acc += g3*w0.w;
        acc += g4*w1.x;  acc += g5*w1.y;  acc += g6*w1.z;  acc += g7*w1.w;
        acc += g8*w2.x;  acc += g9*w2.y;  acc += g10*w2.z; acc += g11*w2.w;
        acc += g12*w3.x; acc += g13*w3.y; acc += g14*w3.z; acc += g15*w3.w;

        // Activation: 0=relu, 1=sigmoid, 2=tanh.
        // sigmoid(x) = 0.5*(1+tanh(x/2)) -> single __expf for both paths.
        const float x = acc;
        float z = (act == 1) ? 0.5f * x : x;
        z = fminf(fmaxf(z, -15.0f), 15.0f);
        const float e  = __expf(-2.0f * z);
        const float th = (1.0f - e) / (1.0f + e);       // tanh(z)
        const float y = (act == 0) ? fmaxf(x, 0.0f)
                       : (act == 1) ? 0.5f * (th + 1.0f)
                                    : th;

        out[(size_t)b * TAPE_N + od] = y;
    }
}

extern "C" void kernel_launch(void* const* d_in, const int* in_sizes, int n_in,
                              void* d_out, int out_size, void* d_ws, size_t ws_size,
                              hipStream_t stream)
{
    const float* tape           = (const float*)d_in[0];
    const float* weights        = (const float*)d_in[1];
    const float* bias           = (const float*)d_in[2];
    const int*   input_indices  = (const int*)d_in[3];
    const int*   output_indices = (const int*)d_in[4];
    const int*   act_ids        = (const int*)d_in[5];
    float*       out            = (float*)d_out;

    // Kernel A: full tape copy (B*TAPE floats = 4,194,304 float4)
    const int n4 = (B_SZ * TAPE_N) / 4;
    copy_tape_kernel<<<2048, 256, 0, stream>>>(
        (const float4*)tape, (float4*)out, n4);

    // Kernel B: 65536 outputs, 64 per block, 4 batch-quarters -> 1024 blocks
    neuron_kernel<<<OUT_N / 64, 256, 0, stream>>>(
        tape, weights, bias, input_indices, output_indices, act_ids, out);
}

// Round 2
// 392.438 us; speedup vs baseline: 1.7748x; 1.7748x over previous
//
#include <hip/hip_runtime.h>

#define B_SZ 64
#define TAPE_N 262144
#define OUT_N 65536
#define FANIN 16
#define XCDS 8
#define ROWS_PER_GROUP (B_SZ / XCDS)   // 8

// ---------------------------------------------------------------------------
// Kernel A: copy the full tape into the output buffer (float4 vectorized).
// Scattered columns get overwritten by the compute kernel afterwards.
// ---------------------------------------------------------------------------
__global__ __launch_bounds__(256) void copy_tape_kernel(
    const float4* __restrict__ src, float4* __restrict__ dst, int n4)
{
    int i = blockIdx.x * blockDim.x + threadIdx.x;
    const int stride = gridDim.x * blockDim.x;
    for (; i < n4; i += stride) dst[i] = src[i];
}

// ---------------------------------------------------------------------------
// Kernel B: gather + dot + activation + scatter, XCD-phased over batch rows.
//
// blockIdx.x % 8 -> XCD group (MI355X round-robins consecutive workgroups
// across the 8 XCDs). Group k handles batch rows [8k, 8k+8) ONLY, one row at
// a time, so the live gather working set per XCD is a single 1 MiB row slice
// (plus skew) -- resident in the 4 MiB per-XCD L2. Each thread owns one
// output neuron: indices/weights live in registers across all 8 rows.
// ---------------------------------------------------------------------------
__global__ __launch_bounds__(256) void neuron_kernel(
    const float* __restrict__ tape,
    const float* __restrict__ weights,
    const float* __restrict__ bias,
    const int*   __restrict__ input_indices,
    const int*   __restrict__ output_indices,
    const int*   __restrict__ act_ids,
    float* __restrict__ out)
{
    const int grp = blockIdx.x & (XCDS - 1);       // XCD group 0..7
    const int j   = blockIdx.x >> 3;               // block within group 0..255
    const int o   = j * 256 + threadIdx.x;         // output neuron id

    // 16 indices + 16 weights for this output neuron, kept in registers for
    // all 8 batch rows. Consecutive o across lanes -> coalesced 64B/lane.
    const int4*   ip = (const int4*)(input_indices + (size_t)o * FANIN);
    const float4* wp = (const float4*)(weights      + (size_t)o * FANIN);
    const int4   i0 = ip[0], i1 = ip[1], i2 = ip[2], i3 = ip[3];
    const float4 w0 = wp[0], w1 = wp[1], w2 = wp[2], w3 = wp[3];
    const float bs  = bias[o];
    const int   act = act_ids[o];
    const int   od  = output_indices[o];

    const int b0 = grp * ROWS_PER_GROUP;
    #pragma unroll 1
    for (int r = 0; r < ROWS_PER_GROUP; ++r) {
        const int b = b0 + r;
        const float* __restrict__ t = tape + (size_t)b * TAPE_N;
        // 16 independent gathers in flight before the first use.
        float g0  = t[i0.x], g1  = t[i0.y], g2  = t[i0.z], g3  = t[i0.w];
        float g4  = t[i1.x], g5  = t[i1.y], g6  = t[i1.z], g7  = t[i1.w];
        float g8  = t[i2.x], g9  = t[i2.y], g10 = t[i2.z], g11 = t[i2.w];
        float g12 = t[i3.x], g13 = t[i3.y], g14 = t[i3.z], g15 = t[i3.w];

        float acc = bs;
        acc += g0*w0.x;  acc += g1*w0.y;  acc += g2*w0.z;  acc += g3*w0.w;
        acc += g4*w1.x;  acc += g5*w1.y;  acc += g6*w1.z;  acc += g7*w1.w;
        acc += g8*w2.x;  acc += g9*w2.y;  acc += g10*w2.z; acc += g11*w2.w;
        acc += g12*w3.x; acc += g13*w3.y; acc += g14*w3.z; acc += g15*w3.w;

        // Activation: 0=relu, 1=sigmoid, 2=tanh.
        // sigmoid(x) = 0.5*(1+tanh(x/2)) -> single __expf for both paths.
        const float x = acc;
        float z = (act == 1) ? 0.5f * x : x;
        z = fminf(fmaxf(z, -15.0f), 15.0f);
        const float e  = __expf(-2.0f * z);
        const float th = (1.0f - e) / (1.0f + e);       // tanh(z)
        const float y = (act == 0) ? fmaxf(x, 0.0f)
                       : (act == 1) ? 0.5f * (th + 1.0f)
                                    : th;

        out[(size_t)b * TAPE_N + od] = y;
    }
}

extern "C" void kernel_launch(void* const* d_in, const int* in_sizes, int n_in,
                              void* d_out, int out_size, void* d_ws, size_t ws_size,
                              hipStream_t stream)
{
    const float* tape           = (const float*)d_in[0];
    const float* weights        = (const float*)d_in[1];
    const float* bias           = (const float*)d_in[2];
    const int*   input_indices  = (const int*)d_in[3];
    const int*   output_indices = (const int*)d_in[4];
    const int*   act_ids        = (const int*)d_in[5];
    float*       out            = (float*)d_out;

    // Kernel A: full tape copy (B*TAPE floats = 4,194,304 float4)
    const int n4 = (B_SZ * TAPE_N) / 4;
    copy_tape_kernel<<<4096, 256, 0, stream>>>(
        (const float4*)tape, (float4*)out, n4);

    // Kernel B: 8 groups x 256 blocks; group = blockIdx%8 -> XCD affinity.
    neuron_kernel<<<XCDS * (OUT_N / 256), 256, 0, stream>>>(
        tape, weights, bias, input_indices, output_indices, act_ids, out);
}

// Round 3
// 206.551 us; speedup vs baseline: 3.3721x; 1.9000x over previous
//
#include <hip/hip_runtime.h>

#define B_SZ 64
#define TAPE_N 262144
#define OUT_N 65536
#define FANIN 16
#define XCDS 8
#define ROWS_PER_GROUP (B_SZ / XCDS)   // 8

// ===========================================================================
// Main path: transpose tape to [TAPE][B] so each (output, fanin) gather is a
// single fully-utilized 64B line per batch-quarter instead of 16 scattered
// 4B touches. d_ws holds tape_T (64 MiB).
// ===========================================================================

// ---------------------------------------------------------------------------
// Kernel 1: fused tape->out copy + LDS-tiled transpose tape -> tape_T[t][b].
// One block per 64-column chunk. Reads/writes fully coalesced (float4).
// ---------------------------------------------------------------------------
__global__ __launch_bounds__(256) void copy_transpose_kernel(
    const float* __restrict__ tape, float* __restrict__ out,
    float* __restrict__ tape_T)
{
    __shared__ float lds[64][65];      // [t_local][b], +1 pad breaks conflicts
    const int t0  = blockIdx.x * 64;
    const int tid = threadIdx.x;

    // Read phase: wave reads 4 rows x 256B contiguous per instruction.
    const int t4 = tid & 15;           // which float4 within the 64-col chunk
    const int b0 = tid >> 4;           // 0..15
    #pragma unroll
    for (int r = 0; r < 4; ++r) {
        const int b = b0 + r * 16;     // 0..63
        const float4 v = *(const float4*)(tape + (size_t)b * TAPE_N + t0 + t4 * 4);
        *(float4*)(out + (size_t)b * TAPE_N + t0 + t4 * 4) = v;
        lds[t4 * 4 + 0][b] = v.x;
        lds[t4 * 4 + 1][b] = v.y;
        lds[t4 * 4 + 2][b] = v.z;
        lds[t4 * 4 + 3][b] = v.w;
    }
    __syncthreads();

    // Write phase: each t row of tape_T is 64 floats = 16 float4, contiguous.
    const int b4  = tid & 15;
    const int tw0 = tid >> 4;
    #pragma unroll
    for (int p = 0; p < 4; ++p) {
        const int t = tw0 + p * 16;
        float4 v;
        v.x = lds[t][b4 * 4 + 0];
        v.y = lds[t][b4 * 4 + 1];
        v.z = lds[t][b4 * 4 + 2];
        v.w = lds[t][b4 * 4 + 3];
        *(float4*)(tape_T + (size_t)(t0 + t) * 64 + b4 * 4) = v;
    }
}

// ---------------------------------------------------------------------------
// Kernel 2: gather from tape_T. thread = (o = blk*64 + tid&63, bq = tid>>6).
// Per fanin index: one 64B-aligned line (4x float4, 3 of 4 are L1 hits),
// accumulate 16 batch rows in registers, activation, coalesced scatter.
// ---------------------------------------------------------------------------
__global__ __launch_bounds__(256) void neuron_t_kernel(
    const float* __restrict__ tape_T,
    const float* __restrict__ weights,
    const float* __restrict__ bias,
    const int*   __restrict__ input_indices,
    const int*   __restrict__ output_indices,
    const int*   __restrict__ act_ids,
    float* __restrict__ out)
{
    const int tid = threadIdx.x;
    const int o   = blockIdx.x * 64 + (tid & 63);
    const int bq  = tid >> 6;                       // 0..3, b = bq*16 + k

    const int4*   ip = (const int4*)(input_indices + (size_t)o * FANIN);
    const float4* wp = (const float4*)(weights      + (size_t)o * FANIN);
    const int4   I0 = ip[0], I1 = ip[1], I2 = ip[2], I3 = ip[3];
    const float4 W0 = wp[0], W1 = wp[1], W2 = wp[2], W3 = wp[3];
    const float bs  = bias[o];
    const int   act = act_ids[o];
    const int   od  = output_indices[o];

    float acc[16];
    #pragma unroll
    for (int k = 0; k < 16; ++k) acc[k] = bs;

    const float* tb = tape_T + bq * 16;             // this quarter's 64B slot

    int   idx[16] = {I0.x, I0.y, I0.z, I0.w, I1.x, I1.y, I1.z, I1.w,
                     I2.x, I2.y, I2.z, I2.w, I3.x, I3.y, I3.z, I3.w};
    float wv[16]  = {W0.x, W0.y, W0.z, W0.w, W1.x, W1.y, W1.z, W1.w,
                     W2.x, W2.y, W2.z, W2.w, W3.x, W3.y, W3.z, W3.w};

    #pragma unroll 4
    for (int f = 0; f < 16; ++f) {
        const float4* seg = (const float4*)(tb + (size_t)idx[f] * 64);
        const float4 v0 = seg[0], v1 = seg[1], v2 = seg[2], v3 = seg[3];
        const float w = wv[f];
        acc[0]  += w * v0.x; acc[1]  += w * v0.y; acc[2]  += w * v0.z; acc[3]  += w * v0.w;
        acc[4]  += w * v1.x; acc[5]  += w * v1.y; acc[6]  += w * v1.z; acc[7]  += w * v1.w;
        acc[8]  += w * v2.x; acc[9]  += w * v2.y; acc[10] += w * v2.z; acc[11] += w * v2.w;
        acc[12] += w * v3.x; acc[13] += w * v3.y; acc[14] += w * v3.z; acc[15] += w * v3.w;
    }

    #pragma unroll
    for (int k = 0; k < 16; ++k) {
        const float x = acc[k];
        float z = (act == 1) ? 0.5f * x : x;
        z = fminf(fmaxf(z, -15.0f), 15.0f);
        const float e  = __expf(-2.0f * z);
        const float th = (1.0f - e) / (1.0f + e);   // tanh(z)
        const float y = (act == 0) ? fmaxf(x, 0.0f)
                       : (act == 1) ? 0.5f * (th + 1.0f)
                                    : th;
        out[(size_t)(bq * 16 + k) * TAPE_N + od] = y;
    }
}

// ===========================================================================
// Fallback path (ws too small): round-2 kernels (XCD-phased scalar gather).
// ===========================================================================
__global__ __launch_bounds__(256) void copy_tape_kernel(
    const float4* __restrict__ src, float4* __restrict__ dst, int n4)
{
    int i = blockIdx.x * blockDim.x + threadIdx.x;
    const int stride = gridDim.x * blockDim.x;
    for (; i < n4; i += stride) dst[i] = src[i];
}

__global__ __launch_bounds__(256) void neuron_kernel(
    const float* __restrict__ tape,
    const float* __restrict__ weights,
    const float* __restrict__ bias,
    const int*   __restrict__ input_indices,
    const int*   __restrict__ output_indices,
    const int*   __restrict__ act_ids,
    float* __restrict__ out)
{
    const int grp = blockIdx.x & (XCDS - 1);
    const int j   = blockIdx.x >> 3;
    const int o   = j * 256 + threadIdx.x;

    const int4*   ip = (const int4*)(input_indices + (size_t)o * FANIN);
    const float4* wp = (const float4*)(weights      + (size_t)o * FANIN);
    const int4   i0 = ip[0], i1 = ip[1], i2 = ip[2], i3 = ip[3];
    const float4 w0 = wp[0], w1 = wp[1], w2 = wp[2], w3 = wp[3];
    const float bs  = bias[o];
    const int   act = act_ids[o];
    const int   od  = output_indices[o];

    const int b0 = grp * ROWS_PER_GROUP;
    #pragma unroll 1
    for (int r = 0; r < ROWS_PER_GROUP; ++r) {
        const int b = b0 + r;
        const float* __restrict__ t = tape + (size_t)b * TAPE_N;
        float g0  = t[i0.x], g1  = t[i0.y], g2  = t[i0.z], g3  = t[i0.w];
        float g4  = t[i1.x], g5  = t[i1.y], g6  = t[i1.z], g7  = t[i1.w];
        float g8  = t[i2.x], g9  = t[i2.y], g10 = t[i2.z], g11 = t[i2.w];
        float g12 = t[i3.x], g13 = t[i3.y], g14 = t[i3.z], g15 = t[i3.w];

        float acc = bs;
        acc += g0*w0.x;  acc += g1*w0.y;  acc += g2*w0.z;  acc += g3*w0.w;
        acc += g4*w1.x;  acc += g5*w1.y;  acc += g6*w1.z;  acc += g7*w1.w;
        acc += g8*w2.x;  acc += g9*w2.y;  acc += g10*w2.z; acc += g11*w2.w;
        acc += g12*w3.x; acc += g13*w3.y; acc += g14*w3.z; acc += g15*w3.w;

        const float x = acc;
        float z = (act == 1) ? 0.5f * x : x;
        z = fminf(fmaxf(z, -15.0f), 15.0f);
        const float e  = __expf(-2.0f * z);
        const float th = (1.0f - e) / (1.0f + e);
        const float y = (act == 0) ? fmaxf(x, 0.0f)
                       : (act == 1) ? 0.5f * (th + 1.0f)
                                    : th;

        out[(size_t)b * TAPE_N + od] = y;
    }
}

extern "C" void kernel_launch(void* const* d_in, const int* in_sizes, int n_in,
                              void* d_out, int out_size, void* d_ws, size_t ws_size,
                              hipStream_t stream)
{
    const float* tape           = (const float*)d_in[0];
    const float* weights        = (const float*)d_in[1];
    const float* bias           = (const float*)d_in[2];
    const int*   input_indices  = (const int*)d_in[3];
    const int*   output_indices = (const int*)d_in[4];
    const int*   act_ids        = (const int*)d_in[5];
    float*       out            = (float*)d_out;

    const size_t need = (size_t)TAPE_N * B_SZ * sizeof(float);   // 64 MiB

    if (ws_size >= need) {
        float* tape_T = (float*)d_ws;
        // Kernel 1: copy + transpose. 262144/64 = 4096 blocks.
        copy_transpose_kernel<<<TAPE_N / 64, 256, 0, stream>>>(tape, out, tape_T);
        // Kernel 2: 64 outputs/block x 4 batch-quarters -> 1024 blocks.
        neuron_t_kernel<<<OUT_N / 64, 256, 0, stream>>>(
            tape_T, weights, bias, input_indices, output_indices, act_ids, out);
    } else {
        const int n4 = (B_SZ * TAPE_N) / 4;
        copy_tape_kernel<<<4096, 256, 0, stream>>>(
            (const float4*)tape, (float4*)out, n4);
        neuron_kernel<<<XCDS * (OUT_N / 256), 256, 0, stream>>>(
            tape, weights, bias, input_indices, output_indices, act_ids, out);
    }
}

// Round 4
// 163.104 us; speedup vs baseline: 4.2704x; 1.2664x over previous
//
#include <hip/hip_runtime.h>
#include <hip/hip_fp16.h>

#define B_SZ 64
#define TAPE_N 262144
#define OUT_N 65536
#define FANIN 16
#define XCDS 8
#define ROWS_PER_GROUP (B_SZ / XCDS)   // 8

typedef _Float16 h16v __attribute__((ext_vector_type(16)));  // 32 B
typedef _Float16 h8v  __attribute__((ext_vector_type(8)));   // 16 B

// ===========================================================================
// Main path: transpose tape to fp16 tape_T[t][b] (row = 64 halfs = 128 B).
// Each (o, f, batch-quarter) gather is one 32 B request carrying 16 batch
// values. d_ws holds tape_T (32 MiB).
// ===========================================================================

// ---------------------------------------------------------------------------
// Kernel 1: fused tape->out copy + LDS-tiled transpose tape -> fp16 tape_T.
// One block per 64-column chunk of the tape.
// ---------------------------------------------------------------------------
__global__ __launch_bounds__(256) void copy_transpose_kernel(
    const float* __restrict__ tape, float* __restrict__ out,
    _Float16* __restrict__ tape_T)
{
    __shared__ float lds[64][65];      // [t_local][b]; pad 65 -> 2-way max
    const int t0  = blockIdx.x * 64;
    const int tid = threadIdx.x;

    // Read phase: float4 per thread, 4 batch rows per iteration; also the
    // verbatim tape->out copy.
    const int t4 = tid & 15;           // which float4 within the 64-col chunk
    const int b0 = tid >> 4;           // 0..15
    #pragma unroll
    for (int r = 0; r < 4; ++r) {
        const int b = b0 + r * 16;     // 0..63
        const float4 v = *(const float4*)(tape + (size_t)b * TAPE_N + t0 + t4 * 4);
        *(float4*)(out + (size_t)b * TAPE_N + t0 + t4 * 4) = v;
        lds[t4 * 4 + 0][b] = v.x;
        lds[t4 * 4 + 1][b] = v.y;
        lds[t4 * 4 + 2][b] = v.z;
        lds[t4 * 4 + 3][b] = v.w;
    }
    __syncthreads();

    // Write phase: row t of tape_T = 64 halfs = 128 B = 8 chunks of 16 B.
    // Wave covers 8 rows x 128 B = 1 KB contiguous per pass.
    const int c    = tid & 7;          // 16B chunk within row
    const int trow = tid >> 3;         // 0..31
    #pragma unroll
    for (int p = 0; p < 2; ++p) {
        const int t = trow + p * 32;
        h8v v;
        #pragma unroll
        for (int j = 0; j < 8; ++j) v[j] = (_Float16)lds[t][c * 8 + j];
        *(h8v*)(tape_T + (size_t)(t0 + t) * 64 + c * 8) = v;
    }
}

// ---------------------------------------------------------------------------
// Kernel 2: gather from fp16 tape_T. Wave = batch-quarter (bq = tid>>6),
// lane = output o. Per fanin index: one 32 B load = 16 batch values.
// ---------------------------------------------------------------------------
__global__ __launch_bounds__(256) void neuron_t_kernel(
    const _Float16* __restrict__ tape_T,
    const float* __restrict__ weights,
    const float* __restrict__ bias,
    const int*   __restrict__ input_indices,
    const int*   __restrict__ output_indices,
    const int*   __restrict__ act_ids,
    float* __restrict__ out)
{
    const int tid = threadIdx.x;
    const int o   = blockIdx.x * 64 + (tid & 63);
    const int bq  = tid >> 6;                       // 0..3, b = bq*16 + k

    const int4*   ip = (const int4*)(input_indices + (size_t)o * FANIN);
    const float4* wp = (const float4*)(weights      + (size_t)o * FANIN);
    const int4   I0 = ip[0], I1 = ip[1], I2 = ip[2], I3 = ip[3];
    const float4 W0 = wp[0], W1 = wp[1], W2 = wp[2], W3 = wp[3];
    const float bs  = bias[o];
    const int   act = act_ids[o];
    const int   od  = output_indices[o];

    float acc[16];
    #pragma unroll
    for (int k = 0; k < 16; ++k) acc[k] = bs;

    const _Float16* tb = tape_T + bq * 16;          // this quarter's 32B slot

    int   idx[16] = {I0.x, I0.y, I0.z, I0.w, I1.x, I1.y, I1.z, I1.w,
                     I2.x, I2.y, I2.z, I2.w, I3.x, I3.y, I3.z, I3.w};
    float wv[16]  = {W0.x, W0.y, W0.z, W0.w, W1.x, W1.y, W1.z, W1.w,
                     W2.x, W2.y, W2.z, W2.w, W3.x, W3.y, W3.z, W3.w};

    #pragma unroll 4
    for (int f = 0; f < 16; ++f) {
        const h16v v = *(const h16v*)(tb + (size_t)idx[f] * 64);
        const float w = wv[f];
        #pragma unroll
        for (int k = 0; k < 16; ++k) acc[k] += w * (float)v[k];
    }

    #pragma unroll
    for (int k = 0; k < 16; ++k) {
        const float x = acc[k];
        float z = (act == 1) ? 0.5f * x : x;
        z = fminf(fmaxf(z, -15.0f), 15.0f);
        const float e  = __expf(-2.0f * z);
        const float th = (1.0f - e) / (1.0f + e);   // tanh(z)
        const float y = (act == 0) ? fmaxf(x, 0.0f)
                       : (act == 1) ? 0.5f * (th + 1.0f)
                                    : th;
        out[(size_t)(bq * 16 + k) * TAPE_N + od] = y;
    }
}

// ===========================================================================
// Fallback path (ws too small): round-2 kernels (XCD-phased scalar gather).
// ===========================================================================
__global__ __launch_bounds__(256) void copy_tape_kernel(
    const float4* __restrict__ src, float4* __restrict__ dst, int n4)
{
    int i = blockIdx.x * blockDim.x + threadIdx.x;
    const int stride = gridDim.x * blockDim.x;
    for (; i < n4; i += stride) dst[i] = src[i];
}

__global__ __launch_bounds__(256) void neuron_kernel(
    const float* __restrict__ tape,
    const float* __restrict__ weights,
    const float* __restrict__ bias,
    const int*   __restrict__ input_indices,
    const int*   __restrict__ output_indices,
    const int*   __restrict__ act_ids,
    float* __restrict__ out)
{
    const int grp = blockIdx.x & (XCDS - 1);
    const int j   = blockIdx.x >> 3;
    const int o   = j * 256 + threadIdx.x;

    const int4*   ip = (const int4*)(input_indices + (size_t)o * FANIN);
    const float4* wp = (const float4*)(weights      + (size_t)o * FANIN);
    const int4   i0 = ip[0], i1 = ip[1], i2 = ip[2], i3 = ip[3];
    const float4 w0 = wp[0], w1 = wp[1], w2 = wp[2], w3 = wp[3];
    const float bs  = bias[o];
    const int   act = act_ids[o];
    const int   od  = output_indices[o];

    const int b0 = grp * ROWS_PER_GROUP;
    #pragma unroll 1
    for (int r = 0; r < ROWS_PER_GROUP; ++r) {
        const int b = b0 + r;
        const float* __restrict__ t = tape + (size_t)b * TAPE_N;
        float g0  = t[i0.x], g1  = t[i0.y], g2  = t[i0.z], g3  = t[i0.w];
        float g4  = t[i1.x], g5  = t[i1.y], g6  = t[i1.z], g7  = t[i1.w];
        float g8  = t[i2.x], g9  = t[i2.y], g10 = t[i2.z], g11 = t[i2.w];
        float g12 = t[i3.x], g13 = t[i3.y], g14 = t[i3.z], g15 = t[i3.w];

        float acc = bs;
        acc += g0*w0.x;  acc += g1*w0.y;  acc += g2*w0.z;  acc += g3*w0.w;
        acc += g4*w1.x;  acc += g5*w1.y;  acc += g6*w1.z;  acc += g7*w1.w;
        acc += g8*w2.x;  acc += g9*w2.y;  acc += g10*w2.z; acc += g11*w2.w;
        acc += g12*w3.x; acc += g13*w3.y; acc += g14*w3.z; acc += g15*w3.w;

        const float x = acc;
        float z = (act == 1) ? 0.5f * x : x;
        z = fminf(fmaxf(z, -15.0f), 15.0f);
        const float e  = __expf(-2.0f * z);
        const float th = (1.0f - e) / (1.0f + e);
        const float y = (act == 0) ? fmaxf(x, 0.0f)
                       : (act == 1) ? 0.5f * (th + 1.0f)
                                    : th;

        out[(size_t)b * TAPE_N + od] = y;
    }
}

extern "C" void kernel_launch(void* const* d_in, const int* in_sizes, int n_in,
                              void* d_out, int out_size, void* d_ws, size_t ws_size,
                              hipStream_t stream)
{
    const float* tape           = (const float*)d_in[0];
    const float* weights        = (const float*)d_in[1];
    const float* bias           = (const float*)d_in[2];
    const int*   input_indices  = (const int*)d_in[3];
    const int*   output_indices = (const int*)d_in[4];
    const int*   act_ids        = (const int*)d_in[5];
    float*       out            = (float*)d_out;

    const size_t need = (size_t)TAPE_N * B_SZ * sizeof(_Float16);  // 32 MiB

    if (ws_size >= need) {
        _Float16* tape_T = (_Float16*)d_ws;
        // Kernel 1: copy + fp16 transpose. 262144/64 = 4096 blocks.
        copy_transpose_kernel<<<TAPE_N / 64, 256, 0, stream>>>(tape, out, tape_T);
        // Kernel 2: 64 outputs/block x 4 batch-quarters -> 1024 blocks.
        neuron_t_kernel<<<OUT_N / 64, 256, 0, stream>>>(
            tape_T, weights, bias, input_indices, output_indices, act_ids, out);
    } else {
        const int n4 = (B_SZ * TAPE_N) / 4;
        copy_tape_kernel<<<4096, 256, 0, stream>>>(
            (const float4*)tape, (float4*)out, n4);
        neuron_kernel<<<XCDS * (OUT_N / 256), 256, 0, stream>>>(
            tape, weights, bias, input_indices, output_indices, act_ids, out);
    }
}